// Round 17
// baseline (422.135 us; speedup 1.0000x reference)
//
#include <hip/hip_runtime.h>

#define N_PTS 131072
#define TILE 64
#define THREADS 256
#define REGION 40960   // per-head perm region (counts ~32.8K, >40 sigma headroom)

typedef __bf16 bf16;
typedef __bf16 bf16x8 __attribute__((ext_vector_type(8)));
typedef float f32x4 __attribute__((ext_vector_type(4)));

// ---------------- workspace layout (bytes) ----------------
#define WS_PERM_OFF   256                        // int perm[4][REGION]
#define WS_WPACK_OFF  (256 + 4 * REGION * 4)     // bf16 packed weights
// packed-weight element offsets (bf16 elements, all [out][K] "transposed")
#define OFF_W0     0          // [256][64]   (k=63 zero pad)
#define OFF_WS     16384      // [3][256][256]
#define OFF_TW0    212992     // [4][256][320] (k: 0..62 pts, 63 zero, 64..319 h)
#define OFF_TWS    540672     // [12][256][256]
#define OFF_FEATW  1327104    // [4][256][256]
#define OFF_VIEWSW 1589248    // [4][128][288] (k: 0..255 feat, 256..282 views, 283..287 zero)
#define TOTAL_PACK 1736704

// ---------------- LDS layout (bytes) ----------------
// H [64][256] bf16 (32KB, base 0) + PER-WAVE PRIVATE B rings: 4 waves x
// 3 bufs x 4KB = 48KB. Total 80KB -> exactly 2 blocks/CU (160KB).
// Private staging is what makes the k-loop BARRIER-FREE: each wave's own
// counted vmcnt guards its own B reads (a wave never reads another wave's
// stage loads), so waves free-run and skew instead of barrier-bursting
// the LDS pipe in lockstep (r16's measured ~1000cy/step overhead).
#define H_BASE 0
#define B_BASE 32768
#define LDS_BYTES 81920

__device__ __forceinline__ unsigned swz(unsigned base, unsigned row, unsigned rowstride,
                                        unsigned kbyte) {
  return (base + row * rowstride + kbyte) ^ ((row & 7u) << 4);
}

// async global->LDS, 16B per lane; LDS dest = wave-uniform base + lane*16
__device__ __forceinline__ void gload_lds16(const bf16* g, char* l) {
  __builtin_amdgcn_global_load_lds(
      (const __attribute__((address_space(1))) void*)g,
      (__attribute__((address_space(3))) void*)l, 16, 0, 0);
}

template <int N>
__device__ __forceinline__ void wait_vm() {
  asm volatile("s_waitcnt vmcnt(%0)" ::"n"(N) : "memory");
}

// ================= weight pack (k-major: coalesced reads) + head scatter ==========
__global__ void k_pack(const float* __restrict__ W0, const float* __restrict__ Ws,
                       const float* __restrict__ tW0, const float* __restrict__ tWs,
                       const float* __restrict__ featW, const float* __restrict__ viewsW,
                       bf16* __restrict__ out, const int* __restrict__ head,
                       int* __restrict__ ctrl, int* __restrict__ perm) {
  int gid = blockIdx.x * blockDim.x + threadIdx.x;
  if (gid < N_PTS) {
    int h = head[gid];
    int lane = threadIdx.x & 63;
    #pragma unroll
    for (int hh = 0; hh < 4; ++hh) {
      unsigned long long m = __ballot(h == hh);
      if (m == 0ull) continue;
      int leader = __builtin_ctzll(m);
      int base = 0;
      if (lane == leader) base = atomicAdd(&ctrl[16 + hh], __popcll(m));
      base = __shfl(base, leader);
      if (h == hh) {
        int rank = __popcll(m & ((1ull << lane) - 1ull));
        perm[hh * REGION + base + rank] = gid;
      }
    }
  }

  for (int idx = gid; idx < TOTAL_PACK; idx += gridDim.x * blockDim.x) {
    float v; int dst;
    if (idx < 16384) {                                   // W0: 64k x 256o
      int k = idx >> 8, o = idx & 255;
      v = (k < 63) ? W0[k * 256 + o] : 0.f;
      dst = OFF_W0 + o * 64 + k;
    } else if (idx < 212992) {                           // Ws: 3 x 256k x 256o
      int i = idx - 16384; int l = i >> 16, r = i & 65535, k = r >> 8, o = r & 255;
      v = Ws[i];
      dst = OFF_WS + l * 65536 + o * 256 + k;
    } else if (idx < 540672) {                           // tW0: 4 x 320k x 256o
      int i = idx - 212992; int h = i / 81920, r = i % 81920, k = r >> 8, o = r & 255;
      v = (k < 63) ? tW0[(h * 319 + k) * 256 + o]
                   : (k == 63 ? 0.f : tW0[(h * 319 + k - 1) * 256 + o]);
      dst = OFF_TW0 + h * 81920 + o * 320 + k;
    } else if (idx < 1327104) {                          // tWs: 12 x 256k x 256o
      int i = idx - 540672; int hj = i >> 16, r = i & 65535, k = r >> 8, o = r & 255;
      v = tWs[i];
      dst = OFF_TWS + hj * 65536 + o * 256 + k;
    } else if (idx < 1589248) {                          // featW: 4 x 256k x 256o
      int i = idx - 1327104; int h = i >> 16, r = i & 65535, k = r >> 8, o = r & 255;
      v = featW[i];
      dst = OFF_FEATW + h * 65536 + o * 256 + k;
    } else {                                             // viewsW: 4 x 288k x 128o
      int i = idx - 1589248; int h = i / 36864, r = i % 36864, k = r >> 7, o = r & 127;
      v = (k < 283) ? viewsW[(h * 283 + k) * 128 + o] : 0.f;
      dst = OFF_VIEWSW + h * 36864 + o * 288 + k;
    }
    out[dst] = (bf16)v;
  }
}

// ================= fused MLP layer: barrier-free self-staged k-loop ==============
// 4 waves, each owns 64 rows x NF*16 cols (NF=4: 64x64, acc = 16 f32x4).
// Per wave per step: issue NF gload_lds16 into ITS OWN ring slot (kc+2),
// wait its own counted vmcnt (2NF steady / NF / 0 tail), ds_read A (H,
// static within layer -> no barrier needed) + B (own region), 4*NF MFMA.
// NO barriers inside the loop; 2 per layer (pre-epilogue s_barrier for the
// in-place H overwrite + post-epilogue __syncthreads).
template <int NF, bool RELU, int RKC, int LKC, bool REG_FIRST, int OUTS>
__device__ __forceinline__ void mfma_layer(char* lds, const bf16* __restrict__ Wt,
                                           int wK, const float* __restrict__ bias,
                                           const bf16x8* aregs, int lane, int wave) {
  const int l15 = lane & 15, l4 = lane >> 4;
  constexpr int KC = RKC + LKC;
  f32x4 acc[4][NF];
  #pragma unroll
  for (int m = 0; m < 4; ++m)
    #pragma unroll
    for (int n = 0; n < NF; ++n) acc[m][n] = (f32x4){0.f, 0.f, 0.f, 0.f};

  const int c0 = wave * (NF * 16);
  const int wbase = B_BASE + wave * 12288;   // private 3 x 4KB ring

  // bias preload (drains during prologue; in-order vmcnt retirement keeps
  // the counted waits below correct even if these linger)
  float bv[NF];
  #pragma unroll
  for (int n = 0; n < NF; ++n) bv[n] = bias[c0 + n * 16 + l15];

  // B read base: slot XOR (l15>>1)&3 is n-invariant (n*16 shifts by 8)
  const int breg = wbase + l15 * 64 + ((l4 ^ ((l15 >> 1) & 3)) << 4);

  // A (H) cursor: +64B/step; XOR swizzle; m via 8192-byte immediates
  unsigned acur = (unsigned)(l15 * 512 + l4 * 16);
  const unsigned axor = (l15 & 7u) << 4;

  // stage source cursors: issue s covers region cols s*16..s*16+15
  const bf16* gsrc[NF];
  #pragma unroll
  for (int s = 0; s < NF; ++s) {
    int op = s * 16 + (lane >> 2);          // region-local out col
    int j = lane & 3;
    gsrc[s] = Wt + (c0 + op) * wK + ((j ^ ((op >> 1) & 3)) << 3);
  }

  // prologue: stage ring0 (kk=0), ring1 (kk=32)
  #pragma unroll
  for (int s = 0; s < NF; ++s) { gload_lds16(gsrc[s], lds + wbase + s * 1024); gsrc[s] += 32; }
  #pragma unroll
  for (int s = 0; s < NF; ++s) { gload_lds16(gsrc[s], lds + wbase + 4096 + s * 1024); gsrc[s] += 32; }

  int rd = 0, st = 8192;

  auto dostep = [&](int kc, const bf16x8* ar) {
    if (kc + 2 < KC) {                      // issue stage(kc+2), then wait
      #pragma unroll
      for (int s = 0; s < NF; ++s) { gload_lds16(gsrc[s], lds + wbase + st + s * 1024); gsrc[s] += 32; }
      st = (st == 8192) ? 0 : st + 4096;
      wait_vm<2 * NF>();                    // own stage(kc) landed; kc+1,kc+2 in flight
    } else if (kc + 1 < KC) {
      wait_vm<NF>();
    } else {
      wait_vm<0>();
    }

    bf16x8 a[4];
    if (ar) {
      #pragma unroll
      for (int m = 0; m < 4; ++m) a[m] = ar[m];
    } else {
      unsigned va = acur ^ axor;
      #pragma unroll
      for (int m = 0; m < 4; ++m) a[m] = *(const bf16x8*)(lds + va + m * 8192);
      acur += 64;
    }
    bf16x8 b[NF];
    #pragma unroll
    for (int n = 0; n < NF; ++n) b[n] = *(const bf16x8*)(lds + breg + rd + n * 1024);
    rd = (rd == 8192) ? 0 : rd + 4096;

    __builtin_amdgcn_s_setprio(1);
    #pragma unroll
    for (int n = 0; n < NF; ++n)
      #pragma unroll
      for (int m = 0; m < 4; ++m)
        acc[m][n] = __builtin_amdgcn_mfma_f32_16x16x32_bf16(a[m], b[n], acc[m][n], 0, 0, 0);
    __builtin_amdgcn_s_setprio(0);
  };

  if constexpr (REG_FIRST && RKC >= 1) dostep(0, aregs);
  if constexpr (REG_FIRST && RKC >= 2) dostep(1, aregs + 4);
  #pragma unroll 1
  for (int kc = (REG_FIRST ? RKC : 0); kc < (REG_FIRST ? KC : LKC); ++kc)
    dostep(kc, nullptr);
  if constexpr (!REG_FIRST && RKC >= 1) dostep(KC - 1, aregs);

  // all waves' H reads done (each wave's reads retire before its MFMAs,
  // which precede its barrier arrival) -> in-place H overwrite safe
  __builtin_amdgcn_s_barrier();

  #pragma unroll
  for (int n = 0; n < NF; ++n) {
    int col = c0 + n * 16 + l15;
    #pragma unroll
    for (int m = 0; m < 4; ++m) {
      #pragma unroll
      for (int j = 0; j < 4; ++j) {
        float v = acc[m][n][j] + bv[n];
        if (RELU) v = fmaxf(v, 0.f);
        int row = m * 16 + l4 * 4 + j;
        *(bf16*)(lds + swz(H_BASE, row, 512, col * 2)) = (bf16)v;
      }
    }
  }
  __syncthreads();  // epilogue visible to next layer's free-running reads
}

// ================= main fused kernel =================
// (256,2): 256-reg honest budget (r11 precedent: no spill at acc=64).
// 2 blocks/CU (LDS-capped at 80KB), 8 waves/CU.
__global__ __launch_bounds__(THREADS, 2) void k_main(
    const float* __restrict__ x, const int* __restrict__ ctrl, const int* __restrict__ perm,
    const bf16* __restrict__ wpack,
    const float* __restrict__ b0, const float* __restrict__ bs,
    const float* __restrict__ tb0p, const float* __restrict__ tbsp,
    const float* __restrict__ featb, const float* __restrict__ alphaW,
    const float* __restrict__ alphab, const float* __restrict__ viewsb,
    const float* __restrict__ rgbW, const float* __restrict__ rgbb,
    float* __restrict__ outp) {
  __shared__ __attribute__((aligned(16))) char lds[LDS_BYTES];

  const int tid = threadIdx.x;
  const int lane = tid & 63, wave = tid >> 6;
  const int l15 = lane & 15, l4 = lane >> 4;

  // ---- fixed-grid head/tile mapping ----
  const int hh = blockIdx.x / (REGION / TILE);
  const int start = (blockIdx.x % (REGION / TILE)) * TILE;
  const int cnt = ctrl[16 + hh];
  if (start >= cnt) return;            // empty tile (uniform exit)
  const int nv = min(TILE, cnt - start);
  const int permbase = hh * REGION + start;

  // ---- pts/views fragments -> registers (wave tile = all 64 rows) ----
  bf16x8 ptsreg[8];    // [rkc*4+m]: row = m*16+l15, k = rkc*32 + l4*8 + j
  bf16x8 viewsreg[4];  // [m]:       row = m*16+l15, k = l4*8 + j (>=27 -> 0)
  #pragma unroll
  for (int m = 0; m < 4; ++m) {
    int row = m * 16 + l15;
    bool valid = (start + row) < cnt;
    int p = valid ? perm[permbase + row] : 0;
    const float* xr = x + p * 90;
    #pragma unroll
    for (int rkc = 0; rkc < 2; ++rkc) {
      int k0 = rkc * 32 + l4 * 8;
      bf16x8 f;
      #pragma unroll
      for (int j = 0; j < 8; ++j) {
        int k = k0 + j;
        f[j] = (bf16)((valid && k < 63) ? xr[k] : 0.f);
      }
      ptsreg[rkc * 4 + m] = f;
    }
    {
      int k0 = l4 * 8;
      bf16x8 f;
      #pragma unroll
      for (int j = 0; j < 8; ++j) {
        int k = k0 + j;
        f[j] = (bf16)((valid && k < 27) ? xr[63 + k] : 0.f);
      }
      viewsreg[m] = f;
    }
  }

  const bf16* W0p    = wpack + OFF_W0;
  const bf16* Wsp    = wpack + OFF_WS;
  const bf16* tW0p   = wpack + OFF_TW0 + hh * 81920;
  const bf16* tWsp   = wpack + OFF_TWS + hh * 3 * 65536;
  const bf16* featWp = wpack + OFF_FEATW + hh * 65536;
  const bf16* viewsWp= wpack + OFF_VIEWSW + hh * 36864;

  // trunk: W0 (A from regs), 3x 256->256 (A from H)
  mfma_layer<4, true, 2, 0, true,  256>(lds, W0p, 64, b0, ptsreg, lane, wave);
  mfma_layer<4, true, 0, 8, false, 256>(lds, Wsp,          256, bs,       nullptr, lane, wave);
  mfma_layer<4, true, 0, 8, false, 256>(lds, Wsp + 65536,  256, bs + 256, nullptr, lane, wave);
  mfma_layer<4, true, 0, 8, false, 256>(lds, Wsp + 131072, 256, bs + 512, nullptr, lane, wave);
  // T0: concat(pts[regs], h[LDS]) 320 -> 256
  mfma_layer<4, true, 2, 8, true,  256>(lds, tW0p, 320, tb0p + hh * 256, ptsreg, lane, wave);

  // head layers
  mfma_layer<4, true, 0, 8, false, 256>(lds, tWsp,          256, tbsp + hh * 768,       nullptr, lane, wave);
  mfma_layer<4, true, 0, 8, false, 256>(lds, tWsp + 65536,  256, tbsp + hh * 768 + 256, nullptr, lane, wave);
  mfma_layer<4, true, 0, 8, false, 256>(lds, tWsp + 131072, 256, tbsp + hh * 768 + 512, nullptr, lane, wave);

  // ---- alpha = ha . alphaW[hh] + alphab (all 4 waves; reads complete
  //      before feat's epilogue barrier, which all waves must reach) ----
  float my_alpha;
  {
    int p = wave * 16 + l15;
    int kq = lane >> 4;
    const float* aW = alphaW + hh * 256;
    float s = 0.f;
    for (int i = 0; i < 8; ++i) {
      int k = kq * 64 + i * 8;
      bf16x8 hv8 = *(const bf16x8*)(lds + swz(H_BASE, p, 512, k * 2));
      #pragma unroll
      for (int j = 0; j < 8; ++j) s += (float)hv8[j] * aW[k + j];
    }
    s += __shfl_xor(s, 16);
    s += __shfl_xor(s, 32);
    my_alpha = s + alphab[hh];
  }

  // feat: 256->256 in-place, NO relu
  mfma_layer<4, false, 0, 8, false, 256>(lds, featWp, 256, featb + hh * 256, nullptr, lane, wave);
  // views: concat(feat[LDS], views[regs]) 288 -> 128, relu, into H cols 0..127
  mfma_layer<2, true, 1, 8, false, 128>(lds, viewsWp, 288, viewsb + hh * 128, viewsreg, lane, wave);

  // ---- rgb = hv . rgbW[hh] + rgbb ; write float4 {r,g,b,alpha} ----
  {
    int p = wave * 16 + l15;
    int kq = lane >> 4;
    const float* rW = rgbW + hh * 128 * 3;
    float r0 = 0.f, r1 = 0.f, r2 = 0.f;
    for (int i = 0; i < 4; ++i) {
      int k = kq * 32 + i * 8;
      bf16x8 hv8 = *(const bf16x8*)(lds + swz(H_BASE, p, 512, k * 2));
      #pragma unroll
      for (int j = 0; j < 8; ++j) {
        float hvf = (float)hv8[j];
        r0 += hvf * rW[(k + j) * 3 + 0];
        r1 += hvf * rW[(k + j) * 3 + 1];
        r2 += hvf * rW[(k + j) * 3 + 2];
      }
    }
    r0 += __shfl_xor(r0, 16); r0 += __shfl_xor(r0, 32);
    r1 += __shfl_xor(r1, 16); r1 += __shfl_xor(r1, 32);
    r2 += __shfl_xor(r2, 16); r2 += __shfl_xor(r2, 32);
    if (kq == 0 && p < nv) {
      int pt = perm[permbase + p];
      float4 o = make_float4(r0 + rgbb[hh * 3 + 0], r1 + rgbb[hh * 3 + 1],
                             r2 + rgbb[hh * 3 + 2], my_alpha);
      *(float4*)(outp + pt * 4) = o;
    }
  }
}

// ================= launch =================
extern "C" void kernel_launch(void* const* d_in, const int* in_sizes, int n_in,
                              void* d_out, int out_size, void* d_ws, size_t ws_size,
                              hipStream_t stream) {
  const float* x      = (const float*)d_in[0];
  const int*   head   = (const int*)d_in[1];
  const float* W0     = (const float*)d_in[2];
  const float* b0     = (const float*)d_in[3];
  const float* Ws     = (const float*)d_in[4];
  const float* bs     = (const float*)d_in[5];
  const float* tW0    = (const float*)d_in[6];
  const float* tb0    = (const float*)d_in[7];
  const float* tWs    = (const float*)d_in[8];
  const float* tbs    = (const float*)d_in[9];
  const float* featW  = (const float*)d_in[10];
  const float* featb  = (const float*)d_in[11];
  const float* alphaW = (const float*)d_in[12];
  const float* alphab = (const float*)d_in[13];
  const float* viewsW = (const float*)d_in[14];
  const float* viewsb = (const float*)d_in[15];
  const float* rgbW   = (const float*)d_in[16];
  const float* rgbb   = (const float*)d_in[17];

  int*  ctrl  = (int*)d_ws;
  int*  perm  = (int*)((char*)d_ws + WS_PERM_OFF);
  bf16* wpack = (bf16*)((char*)d_ws + WS_WPACK_OFF);

  hipMemsetAsync(ctrl, 0, 256, stream);
  k_pack<<<2048, 256, 0, stream>>>(W0, Ws, tW0, tWs, featW, viewsW, wpack, head, ctrl, perm);
  k_main<<<4 * (REGION / TILE), THREADS, 0, stream>>>(x, ctrl, perm, wpack,
                                                      b0, bs, tb0, tbs, featb, alphaW, alphab,
                                                      viewsb, rgbW, rgbb, (float*)d_out);
}